// Round 24
// baseline (280.496 us; speedup 1.0000x reference)
//
#include <hip/hip_runtime.h>
#include <stdint.h>

// ---------------------------------------------------------------------------
// TransformerEncoderLayer: b=4 s=2048 d=128 h=8 (head_dim=128) dff=2048
// Round-24 (r23 green 275.7us):
//  - k_ffn: 8-wave M-SPLIT (wave group mt=w>>2 owns one 16-row M-tile; 4-wave
//    dff-split within group; NO cross-group reduce, no atomics). 2 waves/SIMD
//    (was 1). LN epilogue on 2 waves. LDS 64KB.
// Everything else byte-identical to r23.
// ---------------------------------------------------------------------------

using f32x4 = __attribute__((ext_vector_type(4))) float;
using s16x8 = __attribute__((ext_vector_type(8))) short;
using s16x4 = __attribute__((ext_vector_type(4))) short;
typedef __bf16 bf16x8 __attribute__((ext_vector_type(8)));

__device__ inline void mfma_bf16(f32x4* acc, s16x8 a, s16x8 b) {
    *acc = __builtin_amdgcn_mfma_f32_16x16x32_bf16(
        __builtin_bit_cast(bf16x8, a), __builtin_bit_cast(bf16x8, b), *acc, 0, 0, 0);
}

__device__ inline short f2bf(float f) {   // RNE f32 -> bf16 bits (prep paths)
    uint32_t u = __builtin_bit_cast(uint32_t, f);
    u += 0x7fffu + ((u >> 16) & 1u);
    return (short)(u >> 16);
}

__device__ inline short f2bf_hw(float f) { // native cast (cvt_pk pairable)
    return __builtin_bit_cast(short, (__bf16)f);
}

__device__ inline float bf2f(short s) {
    return __builtin_bit_cast(float, (uint32_t)((uint16_t)s) << 16);
}

// async global->LDS, 16B per lane; LDS dest = wave-uniform base + lane*16
__device__ inline void gload16(const short* g, short* l) {
    __builtin_amdgcn_global_load_lds(
        (const __attribute__((address_space(1))) void*)g,
        (__attribute__((address_space(3))) void*)l, 16, 0, 0);
}

// ---------------- ALL weight transposes, one launch ------------------------
__global__ __launch_bounds__(256) void k_transpose_all(
    const float* __restrict__ Wq, const float* __restrict__ Wk,
    const float* __restrict__ Wv, const float* __restrict__ Wo,
    const float* __restrict__ W1, const float* __restrict__ W2,
    short* __restrict__ WqT, short* __restrict__ WkT, short* __restrict__ WvT,
    short* __restrict__ WoT, short* __restrict__ W1T, short* __restrict__ W2T)
{
    int b = blockIdx.x;
    const float* w; short* wt; int R, lc, lb;
    if (b < 512)       { w = Wq; wt = WqT; R = 128;  lc = 10; lb = 0;    }
    else if (b < 1024) { w = Wk; wt = WkT; R = 128;  lc = 10; lb = 512;  }
    else if (b < 1536) { w = Wv; wt = WvT; R = 128;  lc = 10; lb = 1024; }
    else if (b < 2048) { w = Wo; wt = WoT; R = 1024; lc = 7;  lb = 1536; }
    else if (b < 3072) { w = W1; wt = W1T; R = 128;  lc = 11; lb = 2048; }
    else               { w = W2; wt = W2T; R = 2048; lc = 7;  lb = 3072; }
    int i = (b - lb) * 256 + threadIdx.x;
    int r = i >> lc, c = i & ((1 << lc) - 1);
    wt[c * R + r] = f2bf(w[i]);
}

// ---------------- QKV projection (one PAIR of batches, 8 heads each) -------
__global__ __launch_bounds__(256) void k_qkv(
    const float* __restrict__ xPair, const short* __restrict__ WqT,
    const short* __restrict__ WkT, const short* __restrict__ WvT,
    short* __restrict__ Qh, short* __restrict__ Kh, short* __restrict__ Vt)
{
    __shared__ __align__(16) short Bls[64 * 128];   // swizzled [col][k]
    const int z = blockIdx.z;
    const int bt = blockIdx.y >> 4;               // batch in pair
    const int n0 = (blockIdx.y & 15) * 64;        // 0..960
    const short* __restrict__ WT = (z == 0) ? WqT : (z == 1) ? WkT : WvT; // [1024][128]
    const int w = threadIdx.x >> 6, lane = threadIdx.x & 63;
    const int g = lane >> 4, li = lane & 15;
    const int m0 = blockIdx.x * 64 + w * 16;
    const float* __restrict__ xB = xPair + (size_t)bt * 2048 * 128;

    #pragma unroll
    for (int c2 = 0; c2 < 4; ++c2) {
        int ci = c2 * 256 + (int)threadIdx.x;
        int row = ci >> 4, cc = ci & 15;
        gload16(WT + (size_t)(n0 + row) * 128 + ((cc ^ (row & 7)) * 8),
                &Bls[(c2 * 256 + w * 64) * 8]);
    }
    __syncthreads();

    f32x4 acc[4] = {};
    #pragma unroll
    for (int ks = 0; ks < 4; ++ks) {
        const float* xr = xB + (size_t)(m0 + li) * 128 + ks * 32 + g * 8;
        float4 v0 = *(const float4*)xr, v1 = *(const float4*)(xr + 4);
        s16x8 a = { f2bf(v0.x), f2bf(v0.y), f2bf(v0.z), f2bf(v0.w),
                    f2bf(v1.x), f2bf(v1.y), f2bf(v1.z), f2bf(v1.w) };
        #pragma unroll
        for (int nt = 0; nt < 4; ++nt) {
            s16x8 bfr = *(const s16x8*)&Bls[(nt * 16 + li) * 128
                                            + (((ks * 4 + g) ^ (li & 7)) * 8)];
            mfma_bf16(&acc[nt], a, bfr);
        }
    }
    // 1/sqrt(128) * log2(e): scores land in log2 domain
    const float sc = (z == 0) ? 0.12751879524622257f : 1.0f;
    #pragma unroll
    for (int nt = 0; nt < 4; ++nt) {
        int col = n0 + nt * 16 + li;              // 0..1023
        int hh = col >> 7, dd = col & 127;        // head, dim
        int bh = bt * 8 + hh;
        if (z == 2) {
            int row0 = m0 + g * 4;                // s, multiple of 4
            int kt = row0 >> 6, so = row0 & 63;
            s16x4 o = { f2bf(acc[nt][0]), f2bf(acc[nt][1]),
                        f2bf(acc[nt][2]), f2bf(acc[nt][3]) };
            *(s16x4*)(Vt + (((size_t)bh * 32 + kt) * 128 + dd) * 64 + so) = o;
        } else {
            short* __restrict__ dst = (z == 0) ? Qh : Kh;
            #pragma unroll
            for (int r = 0; r < 4; ++r)
                dst[((size_t)bh * 2048 + m0 + g * 4 + r) * 128 + dd] =
                    f2bf(acc[nt][r] * sc);
        }
    }
}

// ---------------- flash attention, 8 waves (QBLK=128), full kv range -------
__global__ __launch_bounds__(512) void k_attn(
    const short* __restrict__ Qh, const short* __restrict__ Kh,
    const short* __restrict__ Vt, short* __restrict__ O)
{
    __shared__ __align__(16) short Kls[2][64 * 128];   // swizzled [k][d], dbuf
    __shared__ __align__(16) short Vls[2][128 * 64];   // swizzled [d][k], dbuf
    __shared__ __align__(16) short Pls[8][16 * 64];    // per-wave swizzled [q][k]
    const int hh = blockIdx.y;
    const int bt = blockIdx.z;
    const int bh = bt * 8 + hh;
    const size_t base  = (size_t)bh * 2048 * 128;
    const size_t vbase = (size_t)bh * 32 * 8192;       // tile-blocked V^T
    const int w = threadIdx.x >> 6, lane = threadIdx.x & 63;
    const int g = lane >> 4, li = lane & 15;
    const int q0 = blockIdx.x * 128;
    const int qw = q0 + w * 16;

    #define STAGE(BUF, KT)                                                      \
        { _Pragma("unroll")                                                     \
          for (int c2 = 0; c2 < 2; ++c2) {                                      \
              int ci = c2 * 512 + (int)threadIdx.x;                             \
              int row = ci >> 4, cc = ci & 15;                                  \
              gload16(Kh + base + (size_t)((KT) * 64 + row) * 128               \
                         + ((cc ^ (row & 7)) * 8),                              \
                      &Kls[BUF][(c2 * 512 + w * 64) * 8]);                      \
              int d = ci >> 3, jc = ci & 7;                                     \
              gload16(Vt + vbase + (size_t)(KT) * 8192 + d * 64                 \
                         + ((jc ^ (d & 7)) * 8),                                \
                      &Vls[BUF][(c2 * 512 + w * 64) * 8]);                      \
          } }

    s16x8 qf[4];
    #pragma unroll
    for (int ks = 0; ks < 4; ++ks)
        qf[ks] = *(const s16x8*)(Qh + base + (size_t)(qw + li) * 128 + ks * 32 + g * 8);

    const s16x8 ones = { 0x3F80, 0x3F80, 0x3F80, 0x3F80,
                         0x3F80, 0x3F80, 0x3F80, 0x3F80 };  // bf16(1.0) x8

    f32x4 acc[8] = {};
    f32x4 acc_l = { 0.f, 0.f, 0.f, 0.f };       // l via ones-MFMA
    float mrow[4] = { -1e30f, -1e30f, -1e30f, -1e30f };

    STAGE(0, 0);
    for (int t = 0; t < 32; ++t) {
        const int cur = t & 1;
        __syncthreads();                  // drains vmcnt: buf[cur] ready
        if (t + 1 < 32) STAGE(cur ^ 1, t + 1);   // in flight during compute

        f32x4 nm = { -mrow[0], -mrow[1], -mrow[2], -mrow[3] };
        f32x4 st[4] = { nm, nm, nm, nm };
        __builtin_amdgcn_s_setprio(1);
        #pragma unroll
        for (int nt = 0; nt < 4; ++nt)
            #pragma unroll
            for (int ks = 0; ks < 4; ++ks) {
                s16x8 bfr = *(const s16x8*)&Kls[cur][(nt * 16 + li) * 128
                                                + (((ks * 4 + g) ^ (li & 7)) * 8)];
                mfma_bf16(&st[nt], qf[ks], bfr);
            }
        __builtin_amdgcn_s_setprio(0);

        float mxl[4];
        bool cond = true;
        #pragma unroll
        for (int r = 0; r < 4; ++r) {
            mxl[r] = fmaxf(fmaxf(st[0][r], st[1][r]), fmaxf(st[2][r], st[3][r]));
            cond = cond && (mxl[r] <= 8.f);
        }
        if (__all(cond)) {
            #pragma unroll
            for (int r = 0; r < 4; ++r)
                #pragma unroll
                for (int nt = 0; nt < 4; ++nt)
                    st[nt][r] = exp2f(st[nt][r]);
        } else {
            #pragma unroll
            for (int r = 0; r < 4; ++r) {
                float mx = mxl[r];
                mx = fmaxf(mx, __shfl_xor(mx, 1));
                mx = fmaxf(mx, __shfl_xor(mx, 2));
                mx = fmaxf(mx, __shfl_xor(mx, 4));
                mx = fmaxf(mx, __shfl_xor(mx, 8));
                float d = fmaxf(mx, 0.f);         // growth of row max (log2)
                float alpha = exp2f(-d);
                #pragma unroll
                for (int nt = 0; nt < 4; ++nt)
                    st[nt][r] = exp2f(st[nt][r] - d);
                mrow[r] += d;
                acc_l[r] *= alpha;
                #pragma unroll
                for (int dt = 0; dt < 8; ++dt) acc[dt][r] *= alpha;
            }
        }

        short* pw = Pls[w];
        #pragma unroll
        for (int nt = 0; nt < 4; ++nt)
            #pragma unroll
            for (int r = 0; r < 4; ++r) {
                int row = g * 4 + r;
                pw[row * 64 + (((nt * 2 + (li >> 3)) ^ (row & 7)) * 8) + (li & 7)]
                    = f2bf_hw(st[nt][r]);
            }
        __builtin_amdgcn_s_setprio(1);
        #pragma unroll
        for (int kk = 0; kk < 2; ++kk) {
            s16x8 af = *(const s16x8*)&pw[li * 64 + (((kk * 4 + g) ^ (li & 7)) * 8)];
            mfma_bf16(&acc_l, af, ones);          // l partial (all cols equal)
            #pragma unroll
            for (int dt = 0; dt < 8; ++dt) {
                s16x8 bfr = *(const s16x8*)&Vls[cur][(dt * 16 + li) * 64
                                                + (((kk * 4 + g) ^ (li & 7)) * 8)];
                mfma_bf16(&acc[dt], af, bfr);
            }
        }
        __builtin_amdgcn_s_setprio(0);
    }
    #undef STAGE

    #pragma unroll
    for (int r = 0; r < 4; ++r) {
        float inv = 1.f / acc_l[r];
        size_t row = (size_t)bt * 2048 + q0 + w * 16 + g * 4 + r;
        #pragma unroll
        for (int dt = 0; dt < 8; ++dt)
            O[row * 1024 + hh * 128 + dt * 16 + li] = f2bf_hw(acc[dt][r] * inv);
    }
}

// ---------------- fused out-proj + residual + LN1 (one PAIR) ---------------
__global__ __launch_bounds__(256) void k_oproj(
    const short* __restrict__ O, const short* __restrict__ WoT,
    const float* __restrict__ resid, const float* __restrict__ gain,
    float* __restrict__ outp)
{
    __shared__ float red[3][16 * 128];            // 24 KB partial-acc dump
    const int w = threadIdx.x >> 6, lane = threadIdx.x & 63;
    const int g = lane >> 4, li = lane & 15;
    const int m0 = blockIdx.x * 16;               // 0..4080
    const int row = m0 + li;
    f32x4 acc[8] = {};
    #pragma unroll
    for (int kq = 0; kq < 8; ++kq) {              // ks = w*8 + kq
        int ks = w * 8 + kq;
        s16x8 a = *(const s16x8*)(O + (size_t)row * 1024 + ks * 32 + g * 8);
        #pragma unroll
        for (int nt = 0; nt < 8; ++nt) {
            s16x8 bfr = *(const s16x8*)(WoT + (size_t)(nt * 16 + li) * 1024
                                           + ks * 32 + g * 8);
            mfma_bf16(&acc[nt], a, bfr);
        }
    }
    if (w > 0) {
        #pragma unroll
        for (int nt = 0; nt < 8; ++nt)
            #pragma unroll
            for (int r = 0; r < 4; ++r)
                red[w - 1][(g * 4 + r) * 128 + nt * 16 + li] = acc[nt][r];
    }
    __syncthreads();
    if (w == 0) {
        float gv[8];
        #pragma unroll
        for (int nt = 0; nt < 8; ++nt) gv[nt] = gain[nt * 16 + li];
        #pragma unroll
        for (int r = 0; r < 4; ++r) {
            int orow = m0 + g * 4 + r;
            float s = 0.f, s2 = 0.f;
            #pragma unroll
            for (int nt = 0; nt < 8; ++nt) {
                float v = acc[nt][r]
                        + red[0][(g * 4 + r) * 128 + nt * 16 + li]
                        + red[1][(g * 4 + r) * 128 + nt * 16 + li]
                        + red[2][(g * 4 + r) * 128 + nt * 16 + li]
                        + resid[(size_t)orow * 128 + nt * 16 + li];
                acc[nt][r] = v;
                s += v; s2 += v * v;
            }
            s  += __shfl_xor(s, 1);  s  += __shfl_xor(s, 2);
            s  += __shfl_xor(s, 4);  s  += __shfl_xor(s, 8);
            s2 += __shfl_xor(s2, 1); s2 += __shfl_xor(s2, 2);
            s2 += __shfl_xor(s2, 4); s2 += __shfl_xor(s2, 8);
            float mean = s * (1.f / 128.f);
            float var  = s2 * (1.f / 128.f) - mean * mean;
            float rstd = rsqrtf(var + 1e-5f);
            #pragma unroll
            for (int nt = 0; nt < 8; ++nt)
                outp[(size_t)orow * 128 + nt * 16 + li] =
                    (acc[nt][r] - mean) * rstd * gv[nt];
        }
    }
}

// ---------------- fused FFN: 8-wave M-split (2 waves/SIMD, no atomics) -----
// ALL batches: grid (64, 4) x 512 thr; block owns 32 rows = 2 M-tiles;
// wave group (mt = w>>2) owns one 16-row tile; 4-wave dff-split per group;
// per-group LDS dump reduce; LN epilogue on 2 waves.
__global__ __launch_bounds__(512) void k_ffn(
    const float* __restrict__ x1, const short* __restrict__ W1T,
    const short* __restrict__ W2T, const float* __restrict__ gain,
    float* __restrict__ outp)
{
    __shared__ __align__(16) short hls[8][16 * 64];   // per wave, 16 KB
    __shared__ float red[2][3][16 * 128];             // [mt][3 waves], 48 KB
    const int w = threadIdx.x >> 6, lane = threadIdx.x & 63;
    const int g = lane >> 4, li = lane & 15;
    const int mt = w >> 2;                        // M-tile of this wave group
    const int wq = w & 3;                         // wave within group
    const size_t m0 = (size_t)blockIdx.y * 2048 + blockIdx.x * 32 + mt * 16;
    s16x8 xf[4];                                  // A-frags for this mt
    #pragma unroll
    for (int ks = 0; ks < 4; ++ks) {
        const float* xr = x1 + (m0 + li) * 128 + ks * 32 + g * 8;
        float4 v0 = *(const float4*)xr, v1 = *(const float4*)(xr + 4);
        xf[ks] = (s16x8){ f2bf(v0.x), f2bf(v0.y), f2bf(v0.z), f2bf(v0.w),
                          f2bf(v1.x), f2bf(v1.y), f2bf(v1.z), f2bf(v1.w) };
    }
    f32x4 acc[8] = {};
    #pragma unroll 2
    for (int cq = 0; cq < 8; ++cq) {              // ch = wq*8 + cq
        int ch = wq * 8 + cq;
        f32x4 st[4] = {};                         // GEMM1: h = relu(x@W1 chunk)
        #pragma unroll
        for (int nt = 0; nt < 4; ++nt)
            #pragma unroll
            for (int ks = 0; ks < 4; ++ks) {
                s16x8 bfr = *(const s16x8*)(W1T + (size_t)(ch * 64 + nt * 16 + li) * 128
                                               + ks * 32 + g * 8);
                mfma_bf16(&st[nt], xf[ks], bfr);
            }
        short* hw = hls[w];
        #pragma unroll
        for (int nt = 0; nt < 4; ++nt)            // stage h -> LDS (P pattern)
            #pragma unroll
            for (int r = 0; r < 4; ++r) {
                int rw = g * 4 + r;
                hw[rw * 64 + (((nt * 2 + (li >> 3)) ^ (rw & 7)) * 8) + (li & 7)]
                    = f2bf_hw(fmaxf(st[nt][r], 0.f));
            }
        #pragma unroll
        for (int kk = 0; kk < 2; ++kk) {          // GEMM2: acc += h @ W2 chunk
            s16x8 af = *(const s16x8*)&hw[li * 64 + (((kk * 4 + g) ^ (li & 7)) * 8)];
            #pragma unroll
            for (int nt = 0; nt < 8; ++nt) {
                s16x8 bfr = *(const s16x8*)(W2T + (size_t)(nt * 16 + li) * 2048
                                               + ch * 64 + kk * 32 + g * 8);
                mfma_bf16(&acc[nt], af, bfr);
            }
        }
    }
    if (wq > 0) {
        #pragma unroll
        for (int nt = 0; nt < 8; ++nt)
            #pragma unroll
            for (int r = 0; r < 4; ++r)
                red[mt][wq - 1][(g * 4 + r) * 128 + nt * 16 + li] = acc[nt][r];
    }
    __syncthreads();
    if (wq == 0) {
        float gv[8];
        #pragma unroll
        for (int nt = 0; nt < 8; ++nt) gv[nt] = gain[nt * 16 + li];
        #pragma unroll
        for (int r = 0; r < 4; ++r) {
            size_t orow = m0 + g * 4 + r;
            float s = 0.f, s2 = 0.f;
            #pragma unroll
            for (int nt = 0; nt < 8; ++nt) {
                float v = acc[nt][r]
                        + red[mt][0][(g * 4 + r) * 128 + nt * 16 + li]
                        + red[mt][1][(g * 4 + r) * 128 + nt * 16 + li]
                        + red[mt][2][(g * 4 + r) * 128 + nt * 16 + li]
                        + x1[orow * 128 + nt * 16 + li];
                acc[nt][r] = v;
                s += v; s2 += v * v;
            }
            s  += __shfl_xor(s, 1);  s  += __shfl_xor(s, 2);
            s  += __shfl_xor(s, 4);  s  += __shfl_xor(s, 8);
            s2 += __shfl_xor(s2, 1); s2 += __shfl_xor(s2, 2);
            s2 += __shfl_xor(s2, 4); s2 += __shfl_xor(s2, 8);
            float mean = s * (1.f / 128.f);
            float var  = s2 * (1.f / 128.f) - mean * mean;
            float rstd = rsqrtf(var + 1e-5f);
            #pragma unroll
            for (int nt = 0; nt < 8; ++nt)
                outp[orow * 128 + nt * 16 + li] = (acc[nt][r] - mean) * rstd * gv[nt];
        }
    }
}

// ---------------------------------------------------------------------------
extern "C" void kernel_launch(void* const* d_in, const int* in_sizes, int n_in,
                              void* d_out, int out_size, void* d_ws, size_t ws_size,
                              hipStream_t stream)
{
    const float* x  = (const float*)d_in[0];
    const float* Wq = (const float*)d_in[1];
    const float* Wk = (const float*)d_in[2];
    const float* Wv = (const float*)d_in[3];
    const float* Wo = (const float*)d_in[4];
    const float* W1 = (const float*)d_in[5];
    const float* W2 = (const float*)d_in[6];
    const float* g1 = (const float*)d_in[7];
    const float* g2 = (const float*)d_in[8];
    float* out = (float*)d_out;
    (void)in_sizes; (void)n_in; (void)out_size; (void)ws_size;

    char* basep = (char*)d_ws;
    size_t off = 0;
    auto carve = [&](size_t bytes) {
        void* q = basep + off;
        off += (bytes + 255) & ~(size_t)255;
        return q;
    };
    // total ~34.3 MiB (proven green in r22/r23)
    short*  WqT = (short*)carve(1024ull * 128 * 2);
    short*  WkT = (short*)carve(1024ull * 128 * 2);
    short*  WvT = (short*)carve(1024ull * 128 * 2);
    short*  WoT = (short*)carve(128ull * 1024 * 2);
    short*  W1T = (short*)carve(2048ull * 128 * 2);
    short*  W2T = (short*)carve(128ull * 2048 * 2);
    short*  Qh  = (short*)carve(16ull * 2048 * 128 * 2);   // 8 MiB (pair)
    short*  Kh  = (short*)carve(16ull * 2048 * 128 * 2);   // 8 MiB
    short*  Vt  = (short*)carve(16ull * 32 * 128 * 64 * 2);// 8 MiB
    short*  O   = (short*)carve(4096ull * 1024 * 2);       // 8 MiB (pair)

    k_transpose_all<<<4096, 256, 0, stream>>>(Wq, Wk, Wv, Wo, W1, W2,
                                              WqT, WkT, WvT, WoT, W1T, W2T);

    for (int p = 0; p < 2; ++p) {
        const float* xp = x + (size_t)p * 4096 * 128;
        float* outp = out + (size_t)p * 4096 * 128;
        k_qkv<<<dim3(32, 32, 3), 256, 0, stream>>>(xp, WqT, WkT, WvT,
                                                   Qh, Kh, Vt);
        k_attn<<<dim3(16, 8, 2), 512, 0, stream>>>(Qh, Kh, Vt, O);
        k_oproj<<<256, 256, 0, stream>>>(O, WoT, xp, g1, outp);
    }

    k_ffn<<<dim3(64, 4), 512, 0, stream>>>(out, W1T, W2T, g2, out);
}

// Round 25
// 275.708 us; speedup vs baseline: 1.0174x; 1.0174x over previous
//
#include <hip/hip_runtime.h>
#include <stdint.h>

// ---------------------------------------------------------------------------
// TransformerEncoderLayer: b=4 s=2048 d=128 h=8 (head_dim=128) dff=2048
// Round-25: consolidation — lock in best-known build (r23, 275.7us).
//  - k_ffn reverted to the r16/r23 proven optimum (4-wave, M=32 weight reuse;
//    the r24 M-split regressed: 2x weight traffic > 2x TLP).
//  - stage A byte-identical to r23: pair-batched qkv (LDS B-staging) ->
//    full-range attn (exp2 softmax, -m C-init, ones-MFMA l, defer-max) ->
//    fused oproj+LN1. FFN+LN2 one launch.
// ---------------------------------------------------------------------------

using f32x4 = __attribute__((ext_vector_type(4))) float;
using s16x8 = __attribute__((ext_vector_type(8))) short;
using s16x4 = __attribute__((ext_vector_type(4))) short;
typedef __bf16 bf16x8 __attribute__((ext_vector_type(8)));

__device__ inline void mfma_bf16(f32x4* acc, s16x8 a, s16x8 b) {
    *acc = __builtin_amdgcn_mfma_f32_16x16x32_bf16(
        __builtin_bit_cast(bf16x8, a), __builtin_bit_cast(bf16x8, b), *acc, 0, 0, 0);
}

__device__ inline short f2bf(float f) {   // RNE f32 -> bf16 bits (prep paths)
    uint32_t u = __builtin_bit_cast(uint32_t, f);
    u += 0x7fffu + ((u >> 16) & 1u);
    return (short)(u >> 16);
}

__device__ inline short f2bf_hw(float f) { // native cast (cvt_pk pairable)
    return __builtin_bit_cast(short, (__bf16)f);
}

__device__ inline float bf2f(short s) {
    return __builtin_bit_cast(float, (uint32_t)((uint16_t)s) << 16);
}

// async global->LDS, 16B per lane; LDS dest = wave-uniform base + lane*16
__device__ inline void gload16(const short* g, short* l) {
    __builtin_amdgcn_global_load_lds(
        (const __attribute__((address_space(1))) void*)g,
        (__attribute__((address_space(3))) void*)l, 16, 0, 0);
}

// ---------------- ALL weight transposes, one launch ------------------------
__global__ __launch_bounds__(256) void k_transpose_all(
    const float* __restrict__ Wq, const float* __restrict__ Wk,
    const float* __restrict__ Wv, const float* __restrict__ Wo,
    const float* __restrict__ W1, const float* __restrict__ W2,
    short* __restrict__ WqT, short* __restrict__ WkT, short* __restrict__ WvT,
    short* __restrict__ WoT, short* __restrict__ W1T, short* __restrict__ W2T)
{
    int b = blockIdx.x;
    const float* w; short* wt; int R, lc, lb;
    if (b < 512)       { w = Wq; wt = WqT; R = 128;  lc = 10; lb = 0;    }
    else if (b < 1024) { w = Wk; wt = WkT; R = 128;  lc = 10; lb = 512;  }
    else if (b < 1536) { w = Wv; wt = WvT; R = 128;  lc = 10; lb = 1024; }
    else if (b < 2048) { w = Wo; wt = WoT; R = 1024; lc = 7;  lb = 1536; }
    else if (b < 3072) { w = W1; wt = W1T; R = 128;  lc = 11; lb = 2048; }
    else               { w = W2; wt = W2T; R = 2048; lc = 7;  lb = 3072; }
    int i = (b - lb) * 256 + threadIdx.x;
    int r = i >> lc, c = i & ((1 << lc) - 1);
    wt[c * R + r] = f2bf(w[i]);
}

// ---------------- QKV projection (one PAIR of batches, 8 heads each) -------
__global__ __launch_bounds__(256) void k_qkv(
    const float* __restrict__ xPair, const short* __restrict__ WqT,
    const short* __restrict__ WkT, const short* __restrict__ WvT,
    short* __restrict__ Qh, short* __restrict__ Kh, short* __restrict__ Vt)
{
    __shared__ __align__(16) short Bls[64 * 128];   // swizzled [col][k]
    const int z = blockIdx.z;
    const int bt = blockIdx.y >> 4;               // batch in pair
    const int n0 = (blockIdx.y & 15) * 64;        // 0..960
    const short* __restrict__ WT = (z == 0) ? WqT : (z == 1) ? WkT : WvT; // [1024][128]
    const int w = threadIdx.x >> 6, lane = threadIdx.x & 63;
    const int g = lane >> 4, li = lane & 15;
    const int m0 = blockIdx.x * 64 + w * 16;
    const float* __restrict__ xB = xPair + (size_t)bt * 2048 * 128;

    #pragma unroll
    for (int c2 = 0; c2 < 4; ++c2) {
        int ci = c2 * 256 + (int)threadIdx.x;
        int row = ci >> 4, cc = ci & 15;
        gload16(WT + (size_t)(n0 + row) * 128 + ((cc ^ (row & 7)) * 8),
                &Bls[(c2 * 256 + w * 64) * 8]);
    }
    __syncthreads();

    f32x4 acc[4] = {};
    #pragma unroll
    for (int ks = 0; ks < 4; ++ks) {
        const float* xr = xB + (size_t)(m0 + li) * 128 + ks * 32 + g * 8;
        float4 v0 = *(const float4*)xr, v1 = *(const float4*)(xr + 4);
        s16x8 a = { f2bf(v0.x), f2bf(v0.y), f2bf(v0.z), f2bf(v0.w),
                    f2bf(v1.x), f2bf(v1.y), f2bf(v1.z), f2bf(v1.w) };
        #pragma unroll
        for (int nt = 0; nt < 4; ++nt) {
            s16x8 bfr = *(const s16x8*)&Bls[(nt * 16 + li) * 128
                                            + (((ks * 4 + g) ^ (li & 7)) * 8)];
            mfma_bf16(&acc[nt], a, bfr);
        }
    }
    // 1/sqrt(128) * log2(e): scores land in log2 domain
    const float sc = (z == 0) ? 0.12751879524622257f : 1.0f;
    #pragma unroll
    for (int nt = 0; nt < 4; ++nt) {
        int col = n0 + nt * 16 + li;              // 0..1023
        int hh = col >> 7, dd = col & 127;        // head, dim
        int bh = bt * 8 + hh;
        if (z == 2) {
            int row0 = m0 + g * 4;                // s, multiple of 4
            int kt = row0 >> 6, so = row0 & 63;
            s16x4 o = { f2bf(acc[nt][0]), f2bf(acc[nt][1]),
                        f2bf(acc[nt][2]), f2bf(acc[nt][3]) };
            *(s16x4*)(Vt + (((size_t)bh * 32 + kt) * 128 + dd) * 64 + so) = o;
        } else {
            short* __restrict__ dst = (z == 0) ? Qh : Kh;
            #pragma unroll
            for (int r = 0; r < 4; ++r)
                dst[((size_t)bh * 2048 + m0 + g * 4 + r) * 128 + dd] =
                    f2bf(acc[nt][r] * sc);
        }
    }
}

// ---------------- flash attention, 8 waves (QBLK=128), full kv range -------
__global__ __launch_bounds__(512) void k_attn(
    const short* __restrict__ Qh, const short* __restrict__ Kh,
    const short* __restrict__ Vt, short* __restrict__ O)
{
    __shared__ __align__(16) short Kls[2][64 * 128];   // swizzled [k][d], dbuf
    __shared__ __align__(16) short Vls[2][128 * 64];   // swizzled [d][k], dbuf
    __shared__ __align__(16) short Pls[8][16 * 64];    // per-wave swizzled [q][k]
    const int hh = blockIdx.y;
    const int bt = blockIdx.z;
    const int bh = bt * 8 + hh;
    const size_t base  = (size_t)bh * 2048 * 128;
    const size_t vbase = (size_t)bh * 32 * 8192;       // tile-blocked V^T
    const int w = threadIdx.x >> 6, lane = threadIdx.x & 63;
    const int g = lane >> 4, li = lane & 15;
    const int q0 = blockIdx.x * 128;
    const int qw = q0 + w * 16;

    #define STAGE(BUF, KT)                                                      \
        { _Pragma("unroll")                                                     \
          for (int c2 = 0; c2 < 2; ++c2) {                                      \
              int ci = c2 * 512 + (int)threadIdx.x;                             \
              int row = ci >> 4, cc = ci & 15;                                  \
              gload16(Kh + base + (size_t)((KT) * 64 + row) * 128               \
                         + ((cc ^ (row & 7)) * 8),                              \
                      &Kls[BUF][(c2 * 512 + w * 64) * 8]);                      \
              int d = ci >> 3, jc = ci & 7;                                     \
              gload16(Vt + vbase + (size_t)(KT) * 8192 + d * 64                 \
                         + ((jc ^ (d & 7)) * 8),                                \
                      &Vls[BUF][(c2 * 512 + w * 64) * 8]);                      \
          } }

    s16x8 qf[4];
    #pragma unroll
    for (int ks = 0; ks < 4; ++ks)
        qf[ks] = *(const s16x8*)(Qh + base + (size_t)(qw + li) * 128 + ks * 32 + g * 8);

    const s16x8 ones = { 0x3F80, 0x3F80, 0x3F80, 0x3F80,
                         0x3F80, 0x3F80, 0x3F80, 0x3F80 };  // bf16(1.0) x8

    f32x4 acc[8] = {};
    f32x4 acc_l = { 0.f, 0.f, 0.f, 0.f };       // l via ones-MFMA
    float mrow[4] = { -1e30f, -1e30f, -1e30f, -1e30f };

    STAGE(0, 0);
    for (int t = 0; t < 32; ++t) {
        const int cur = t & 1;
        __syncthreads();                  // drains vmcnt: buf[cur] ready
        if (t + 1 < 32) STAGE(cur ^ 1, t + 1);   // in flight during compute

        f32x4 nm = { -mrow[0], -mrow[1], -mrow[2], -mrow[3] };
        f32x4 st[4] = { nm, nm, nm, nm };
        __builtin_amdgcn_s_setprio(1);
        #pragma unroll
        for (int nt = 0; nt < 4; ++nt)
            #pragma unroll
            for (int ks = 0; ks < 4; ++ks) {
                s16x8 bfr = *(const s16x8*)&Kls[cur][(nt * 16 + li) * 128
                                                + (((ks * 4 + g) ^ (li & 7)) * 8)];
                mfma_bf16(&st[nt], qf[ks], bfr);
            }
        __builtin_amdgcn_s_setprio(0);

        float mxl[4];
        bool cond = true;
        #pragma unroll
        for (int r = 0; r < 4; ++r) {
            mxl[r] = fmaxf(fmaxf(st[0][r], st[1][r]), fmaxf(st[2][r], st[3][r]));
            cond = cond && (mxl[r] <= 8.f);
        }
        if (__all(cond)) {
            #pragma unroll
            for (int r = 0; r < 4; ++r)
                #pragma unroll
                for (int nt = 0; nt < 4; ++nt)
                    st[nt][r] = exp2f(st[nt][r]);
        } else {
            #pragma unroll
            for (int r = 0; r < 4; ++r) {
                float mx = mxl[r];
                mx = fmaxf(mx, __shfl_xor(mx, 1));
                mx = fmaxf(mx, __shfl_xor(mx, 2));
                mx = fmaxf(mx, __shfl_xor(mx, 4));
                mx = fmaxf(mx, __shfl_xor(mx, 8));
                float d = fmaxf(mx, 0.f);         // growth of row max (log2)
                float alpha = exp2f(-d);
                #pragma unroll
                for (int nt = 0; nt < 4; ++nt)
                    st[nt][r] = exp2f(st[nt][r] - d);
                mrow[r] += d;
                acc_l[r] *= alpha;
                #pragma unroll
                for (int dt = 0; dt < 8; ++dt) acc[dt][r] *= alpha;
            }
        }

        short* pw = Pls[w];
        #pragma unroll
        for (int nt = 0; nt < 4; ++nt)
            #pragma unroll
            for (int r = 0; r < 4; ++r) {
                int row = g * 4 + r;
                pw[row * 64 + (((nt * 2 + (li >> 3)) ^ (row & 7)) * 8) + (li & 7)]
                    = f2bf_hw(st[nt][r]);
            }
        __builtin_amdgcn_s_setprio(1);
        #pragma unroll
        for (int kk = 0; kk < 2; ++kk) {
            s16x8 af = *(const s16x8*)&pw[li * 64 + (((kk * 4 + g) ^ (li & 7)) * 8)];
            mfma_bf16(&acc_l, af, ones);          // l partial (all cols equal)
            #pragma unroll
            for (int dt = 0; dt < 8; ++dt) {
                s16x8 bfr = *(const s16x8*)&Vls[cur][(dt * 16 + li) * 64
                                                + (((kk * 4 + g) ^ (li & 7)) * 8)];
                mfma_bf16(&acc[dt], af, bfr);
            }
        }
        __builtin_amdgcn_s_setprio(0);
    }
    #undef STAGE

    #pragma unroll
    for (int r = 0; r < 4; ++r) {
        float inv = 1.f / acc_l[r];
        size_t row = (size_t)bt * 2048 + q0 + w * 16 + g * 4 + r;
        #pragma unroll
        for (int dt = 0; dt < 8; ++dt)
            O[row * 1024 + hh * 128 + dt * 16 + li] = f2bf_hw(acc[dt][r] * inv);
    }
}

// ---------------- fused out-proj + residual + LN1 (one PAIR) ---------------
__global__ __launch_bounds__(256) void k_oproj(
    const short* __restrict__ O, const short* __restrict__ WoT,
    const float* __restrict__ resid, const float* __restrict__ gain,
    float* __restrict__ outp)
{
    __shared__ float red[3][16 * 128];            // 24 KB partial-acc dump
    const int w = threadIdx.x >> 6, lane = threadIdx.x & 63;
    const int g = lane >> 4, li = lane & 15;
    const int m0 = blockIdx.x * 16;               // 0..4080
    const int row = m0 + li;
    f32x4 acc[8] = {};
    #pragma unroll
    for (int kq = 0; kq < 8; ++kq) {              // ks = w*8 + kq
        int ks = w * 8 + kq;
        s16x8 a = *(const s16x8*)(O + (size_t)row * 1024 + ks * 32 + g * 8);
        #pragma unroll
        for (int nt = 0; nt < 8; ++nt) {
            s16x8 bfr = *(const s16x8*)(WoT + (size_t)(nt * 16 + li) * 1024
                                           + ks * 32 + g * 8);
            mfma_bf16(&acc[nt], a, bfr);
        }
    }
    if (w > 0) {
        #pragma unroll
        for (int nt = 0; nt < 8; ++nt)
            #pragma unroll
            for (int r = 0; r < 4; ++r)
                red[w - 1][(g * 4 + r) * 128 + nt * 16 + li] = acc[nt][r];
    }
    __syncthreads();
    if (w == 0) {
        float gv[8];
        #pragma unroll
        for (int nt = 0; nt < 8; ++nt) gv[nt] = gain[nt * 16 + li];
        #pragma unroll
        for (int r = 0; r < 4; ++r) {
            int orow = m0 + g * 4 + r;
            float s = 0.f, s2 = 0.f;
            #pragma unroll
            for (int nt = 0; nt < 8; ++nt) {
                float v = acc[nt][r]
                        + red[0][(g * 4 + r) * 128 + nt * 16 + li]
                        + red[1][(g * 4 + r) * 128 + nt * 16 + li]
                        + red[2][(g * 4 + r) * 128 + nt * 16 + li]
                        + resid[(size_t)orow * 128 + nt * 16 + li];
                acc[nt][r] = v;
                s += v; s2 += v * v;
            }
            s  += __shfl_xor(s, 1);  s  += __shfl_xor(s, 2);
            s  += __shfl_xor(s, 4);  s  += __shfl_xor(s, 8);
            s2 += __shfl_xor(s2, 1); s2 += __shfl_xor(s2, 2);
            s2 += __shfl_xor(s2, 4); s2 += __shfl_xor(s2, 8);
            float mean = s * (1.f / 128.f);
            float var  = s2 * (1.f / 128.f) - mean * mean;
            float rstd = rsqrtf(var + 1e-5f);
            #pragma unroll
            for (int nt = 0; nt < 8; ++nt)
                outp[(size_t)orow * 128 + nt * 16 + li] =
                    (acc[nt][r] - mean) * rstd * gv[nt];
        }
    }
}

// ---------------- fused FFN (r16/r23 proven optimum, 63us) -----------------
__global__ __launch_bounds__(256) void k_ffn(
    const float* __restrict__ x1, const short* __restrict__ W1T,
    const short* __restrict__ W2T, const float* __restrict__ gain,
    float* __restrict__ outp)
{
    __shared__ __align__(16) short hls[4][2][16 * 64]; // [wave][mt], swizzled
    __shared__ float red[3][2][16 * 128];              // 48 KB partial-acc dump
    const int w = threadIdx.x >> 6, lane = threadIdx.x & 63;
    const int g = lane >> 4, li = lane & 15;
    const size_t m0 = (size_t)blockIdx.y * 2048 + blockIdx.x * 32;
    s16x8 xf[2][4];
    #pragma unroll
    for (int mt = 0; mt < 2; ++mt)
        #pragma unroll
        for (int ks = 0; ks < 4; ++ks) {
            const float* xr = x1 + (m0 + mt * 16 + li) * 128 + ks * 32 + g * 8;
            float4 v0 = *(const float4*)xr, v1 = *(const float4*)(xr + 4);
            xf[mt][ks] = (s16x8){ f2bf(v0.x), f2bf(v0.y), f2bf(v0.z), f2bf(v0.w),
                                  f2bf(v1.x), f2bf(v1.y), f2bf(v1.z), f2bf(v1.w) };
        }
    f32x4 acc[2][8] = {};
    #pragma unroll 2
    for (int cq = 0; cq < 8; ++cq) {              // ch = w*8 + cq
        int ch = w * 8 + cq;
        f32x4 st[2][4] = {};
        #pragma unroll
        for (int nt = 0; nt < 4; ++nt)
            #pragma unroll
            for (int ks = 0; ks < 4; ++ks) {
                s16x8 bfr = *(const s16x8*)(W1T + (size_t)(ch * 64 + nt * 16 + li) * 128
                                               + ks * 32 + g * 8);
                mfma_bf16(&st[0][nt], xf[0][ks], bfr);
                mfma_bf16(&st[1][nt], xf[1][ks], bfr);
            }
        #pragma unroll
        for (int mt = 0; mt < 2; ++mt) {
            short* hw = hls[w][mt];
            #pragma unroll
            for (int nt = 0; nt < 4; ++nt)
                #pragma unroll
                for (int r = 0; r < 4; ++r) {
                    int rw = g * 4 + r;
                    hw[rw * 64 + (((nt * 2 + (li >> 3)) ^ (rw & 7)) * 8) + (li & 7)]
                        = f2bf_hw(fmaxf(st[mt][nt][r], 0.f));
                }
        }
        #pragma unroll
        for (int kk = 0; kk < 2; ++kk) {
            s16x8 af0 = *(const s16x8*)&hls[w][0][li * 64
                                                  + (((kk * 4 + g) ^ (li & 7)) * 8)];
            s16x8 af1 = *(const s16x8*)&hls[w][1][li * 64
                                                  + (((kk * 4 + g) ^ (li & 7)) * 8)];
            #pragma unroll
            for (int nt = 0; nt < 8; ++nt) {
                s16x8 bfr = *(const s16x8*)(W2T + (size_t)(nt * 16 + li) * 2048
                                               + ch * 64 + kk * 32 + g * 8);
                mfma_bf16(&acc[0][nt], af0, bfr);
                mfma_bf16(&acc[1][nt], af1, bfr);
            }
        }
    }
    if (w > 0) {
        #pragma unroll
        for (int mt = 0; mt < 2; ++mt)
            #pragma unroll
            for (int nt = 0; nt < 8; ++nt)
                #pragma unroll
                for (int r = 0; r < 4; ++r)
                    red[w - 1][mt][(g * 4 + r) * 128 + nt * 16 + li] = acc[mt][nt][r];
    }
    __syncthreads();
    if (w == 0) {
        float gv[8];
        #pragma unroll
        for (int nt = 0; nt < 8; ++nt) gv[nt] = gain[nt * 16 + li];
        #pragma unroll
        for (int mt = 0; mt < 2; ++mt)
            #pragma unroll
            for (int r = 0; r < 4; ++r) {
                size_t orow = m0 + mt * 16 + g * 4 + r;
                float s = 0.f, s2 = 0.f;
                #pragma unroll
                for (int nt = 0; nt < 8; ++nt) {
                    float v = acc[mt][nt][r]
                            + red[0][mt][(g * 4 + r) * 128 + nt * 16 + li]
                            + red[1][mt][(g * 4 + r) * 128 + nt * 16 + li]
                            + red[2][mt][(g * 4 + r) * 128 + nt * 16 + li]
                            + x1[orow * 128 + nt * 16 + li];
                    acc[mt][nt][r] = v;
                    s += v; s2 += v * v;
                }
                s  += __shfl_xor(s, 1);  s  += __shfl_xor(s, 2);
                s  += __shfl_xor(s, 4);  s  += __shfl_xor(s, 8);
                s2 += __shfl_xor(s2, 1); s2 += __shfl_xor(s2, 2);
                s2 += __shfl_xor(s2, 4); s2 += __shfl_xor(s2, 8);
                float mean = s * (1.f / 128.f);
                float var  = s2 * (1.f / 128.f) - mean * mean;
                float rstd = rsqrtf(var + 1e-5f);
                #pragma unroll
                for (int nt = 0; nt < 8; ++nt)
                    outp[orow * 128 + nt * 16 + li] =
                        (acc[mt][nt][r] - mean) * rstd * gv[nt];
            }
    }
}

// ---------------------------------------------------------------------------
extern "C" void kernel_launch(void* const* d_in, const int* in_sizes, int n_in,
                              void* d_out, int out_size, void* d_ws, size_t ws_size,
                              hipStream_t stream)
{
    const float* x  = (const float*)d_in[0];
    const float* Wq = (const float*)d_in[1];
    const float* Wk = (const float*)d_in[2];
    const float* Wv = (const float*)d_in[3];
    const float* Wo = (const float*)d_in[4];
    const float* W1 = (const float*)d_in[5];
    const float* W2 = (const float*)d_in[6];
    const float* g1 = (const float*)d_in[7];
    const float* g2 = (const float*)d_in[8];
    float* out = (float*)d_out;
    (void)in_sizes; (void)n_in; (void)out_size; (void)ws_size;

    char* basep = (char*)d_ws;
    size_t off = 0;
    auto carve = [&](size_t bytes) {
        void* q = basep + off;
        off += (bytes + 255) & ~(size_t)255;
        return q;
    };
    // total ~34.3 MiB (proven green in r22/r23/r24)
    short*  WqT = (short*)carve(1024ull * 128 * 2);
    short*  WkT = (short*)carve(1024ull * 128 * 2);
    short*  WvT = (short*)carve(1024ull * 128 * 2);
    short*  WoT = (short*)carve(128ull * 1024 * 2);
    short*  W1T = (short*)carve(2048ull * 128 * 2);
    short*  W2T = (short*)carve(128ull * 2048 * 2);
    short*  Qh  = (short*)carve(16ull * 2048 * 128 * 2);   // 8 MiB (pair)
    short*  Kh  = (short*)carve(16ull * 2048 * 128 * 2);   // 8 MiB
    short*  Vt  = (short*)carve(16ull * 32 * 128 * 64 * 2);// 8 MiB
    short*  O   = (short*)carve(4096ull * 1024 * 2);       // 8 MiB (pair)

    k_transpose_all<<<4096, 256, 0, stream>>>(Wq, Wk, Wv, Wo, W1, W2,
                                              WqT, WkT, WvT, WoT, W1T, W2T);

    for (int p = 0; p < 2; ++p) {
        const float* xp = x + (size_t)p * 4096 * 128;
        float* outp = out + (size_t)p * 4096 * 128;
        k_qkv<<<dim3(32, 32, 3), 256, 0, stream>>>(xp, WqT, WkT, WvT,
                                                   Qh, Kh, Vt);
        k_attn<<<dim3(16, 8, 2), 512, 0, stream>>>(Qh, Kh, Vt, O);
        k_oproj<<<256, 256, 0, stream>>>(O, WoT, xp, g1, outp);
    }

    k_ffn<<<dim3(64, 4), 256, 0, stream>>>(out, W1T, W2T, g2, out);
}